// Round 4
// baseline (182.339 us; speedup 1.0000x reference)
//
#include <hip/hip_runtime.h>

// IndependentMLP: x(4096,1024), w0(1024,1,16), w1(1024,16,16), wf(1024,16,8)
// out[b,i,j] = sum_k tanh( sum_l tanh(x[b,i]*w0[i,l]) * w1[i,l,k] ) * wf[i,k,j]
//
// R3 -> R4: R3 ran ~67us (inferred: dur 182 - ~115us harness fill overhead)
// at only 4 waves/SIMD. Dependency-stall theory: long tanh->MFMA->tanh->MFMA
// chains need more co-resident waves. Changes:
//   1. grid 2048 (32 batch splits x 64 i-groups) -> 8 waves/SIMD.
//   2. fold 2*log2e tanh scale into w0 / w1 fragments (setup-time) -- removes
//      8 dependent v_mul per (t,ii), shortens the critical chain.
//   3. unroll t by 2 for cross-iteration ILP.
//
// Verified structure (R1-R3, absmax 0.0625): transposed tiny-GEMMs on
// v_mfma_f32_16x16x16f16; MFMA1 C/D layout == MFMA2 B layout so layer-2 tanh
// is applied in-register. Each wave owns 4 consecutive i's (one float4 x-load
// per lane); block's 4 waves cover 16 i's = one full 64B x line.

typedef _Float16 half4 __attribute__((ext_vector_type(4)));
typedef float f32x4 __attribute__((ext_vector_type(4)));

#define TANH_SCALE 2.885390081777927f  // 2*log2(e)

__device__ __forceinline__ float tanh_prescaled(float xs) {
  // xs = x * 2*log2e already applied; tanh(x) = 1 - 2/(exp2(xs)+1)
  float e = __builtin_amdgcn_exp2f(xs);
  return 1.0f - 2.0f * __builtin_amdgcn_rcpf(e + 1.0f);
}

__global__ __launch_bounds__(256) void mlp_fused(const float* __restrict__ x,
                                                 const float* __restrict__ w0,
                                                 const float* __restrict__ w1,
                                                 const float* __restrict__ wf,
                                                 float* __restrict__ out) {
  const int tid = threadIdx.x;
  const int wid = tid >> 6;         // wave 0..3
  const int lane = tid & 63;
  const int g = lane >> 4;          // 0..3 (k-group)
  const int r = lane & 15;          // batch-row / n / j slot
  const int ig = blockIdx.x & 63;   // i-group of 16
  const int bs = blockIdx.x >> 6;   // batch split 0..31 (128 rows each)
  const int i0 = ig * 16 + wid * 4; // this wave's 4 i's
  const int bbase = bs * 128;

  // Weight fragments for 4 i's. Scale folded into w0/w1 so both tanh args
  // arrive pre-scaled by 2*log2e.
  half4 aw1[4];   // A1 = (S*w1)^T: [row=n=r][k=4g+kk]
  half4 awf[4];   // A2 = wf^T: [row=j=r][k2=4g+kk], 0 for r>=8
  f32x4 w0v[4];   // S * w0[i][4g..4g+3]
#pragma unroll
  for (int ii = 0; ii < 4; ++ii) {
    const int i = i0 + ii;
    const float* w1p = w1 + i * 256 + g * 64 + r;
#pragma unroll
    for (int k = 0; k < 4; ++k) aw1[ii][k] = (_Float16)(w1p[k * 16] * TANH_SCALE);
    const float* wfp = wf + i * 128 + g * 32 + r;
#pragma unroll
    for (int k = 0; k < 4; ++k)
      awf[ii][k] = (r < 8) ? (_Float16)wfp[k * 8] : (_Float16)0.0f;
    f32x4 wv = *(const f32x4*)(w0 + i * 16 + g * 4);
#pragma unroll
    for (int k = 0; k < 4; ++k) w0v[ii][k] = wv[k] * TANH_SCALE;
  }

  // lane r: float4 covering x[b][i0..i0+3]; g-groups broadcast same address.
  const float* xp = x + (size_t)(bbase + r) * 1024 + i0;
  float* op = out + (size_t)(bbase + r) * 8192 + i0 * 8 + g * 4;

  const f32x4 zero = {0.f, 0.f, 0.f, 0.f};
  const bool do_store = (g < 2);

  // software pipeline depth 2
  f32x4 xa = *(const f32x4*)(xp);
  f32x4 xb = *(const f32x4*)(xp + 16 * 1024);

#pragma unroll 2
  for (int t = 0; t < 8; ++t) {
    const int tn = (t + 2 < 8) ? t + 2 : 7;  // clamped prefetch (uniform)
    f32x4 xn = *(const f32x4*)(xp + (size_t)tn * 16 * 1024);

#pragma unroll
    for (int ii = 0; ii < 4; ++ii) {
      // h1^T (B1): [k=4g+kk][m=r] = tanh(x * w0) with pre-scaled args
      half4 bh1;
#pragma unroll
      for (int k = 0; k < 4; ++k)
        bh1[k] = (_Float16)tanh_prescaled(xa[ii] * w0v[ii][k]);
      // D1[n=4g+kk][m=r] = (S*w1)^T @ h1^T  (pre-scaled preact2)
      f32x4 d1 = __builtin_amdgcn_mfma_f32_16x16x16f16(aw1[ii], bh1, zero, 0, 0, 0);
      // h2^T (B2) = tanh of unscaled preact2 == tanh_prescaled(d1)
      half4 bh2;
#pragma unroll
      for (int k = 0; k < 4; ++k) bh2[k] = (_Float16)tanh_prescaled(d1[k]);
      // D2[j=4g+kk][m=r] = wf^T @ h2^T (valid j<8 -> g<2)
      f32x4 d2 = __builtin_amdgcn_mfma_f32_16x16x16f16(awf[ii], bh2, zero, 0, 0, 0);
      if (do_store)
        *(f32x4*)(op + (size_t)t * 16 * 8192 + ii * 8) = d2;
    }
    xa = xb;
    xb = xn;
  }
}

extern "C" void kernel_launch(void* const* d_in, const int* in_sizes, int n_in,
                              void* d_out, int out_size, void* d_ws, size_t ws_size,
                              hipStream_t stream) {
  const float* x = (const float*)d_in[0];
  const float* w0 = (const float*)d_in[1];
  const float* w1 = (const float*)d_in[2];
  const float* wf = (const float*)d_in[3];
  float* out = (float*)d_out;
  (void)d_ws; (void)ws_size;
  mlp_fused<<<2048, 256, 0, stream>>>(x, w0, w1, wf, out);
}